// Round 9
// baseline (80.167 us; speedup 1.0000x reference)
//
#include <hip/hip_runtime.h>

#define GDIM 76
#define GG   5776
#define DDIM 85
#define ADIM 3
#define LDSW 77            // lane stride 77 ≡ 13 (mod 32) -> conflict-free scalar LDS access
#define NV4  1615          // = 19 * 85 = DDIM*GDIM/4
#define ROWV4 19
#define PLANE (DDIM * GG)
#define ITERS 7            // 6 full + 1 tail (tid < 79)

// Round-5 structure (best: 64.7 us), single change: PLAIN stores instead of
// nontemporal (isolating the nt knob that was confounded in round 3->5).
__global__ __launch_bounds__(256, 6) void yolo_kernel(const float* __restrict__ x,
                                                      float* __restrict__ out) {
    // XCD swizzle: 7296 = 8 * 912, bijective; each XCD owns 912 consecutive tiles.
    const int cpx = gridDim.x >> 3;
    const int blk = (blockIdx.x & 7) * cpx + (blockIdx.x >> 3);

    const int i    = blk % GDIM;
    const int slab = blk / GDIM;   // b*A + a
    const int a    = slab % ADIM;
    const int tid  = threadIdx.x;

    __shared__ float lds[DDIM * LDSW];   // 26180 B -> 6 blocks/CU

    const float aw  = (a == 0) ? 10.0f : (a == 1) ? 16.0f : 33.0f;
    const float ah  = (a == 0) ? 13.0f : (a == 1) ? 30.0f : 23.0f;
    const float fi8 = (float)i * 8.0f;

    const float* __restrict__ src = x + (size_t)slab * PLANE + i * GDIM;
    float* __restrict__ dst = out + (size_t)slab * PLANE + (size_t)i * (GDIM * DDIM);

    // ---- phase 1a: issue ALL coalesced float4 loads back-to-back (max MLP) ----
    float4 v[ITERS];
    #pragma unroll
    for (int it = 0; it < ITERS; ++it) {
        const int idx = tid + it * 256;
        if (it < 6 || idx < NV4) {
            const int d = idx / ROWV4;           // magic-mul div by 19
            const int k = idx - d * ROWV4;
            v[it] = *(const float4*)(src + (size_t)d * GG + 4 * k);
        }
    }

    // ---- phase 1b: activation + contiguous LDS writes (~2-way, near-free) ----
    #pragma unroll
    for (int it = 0; it < ITERS; ++it) {
        const int idx = tid + it * 256;
        if (it < 6 || idx < NV4) {
            const int d = idx / ROWV4;
            const int k = idx - d * ROWV4;
            const bool iswh = (d == 3) | (d == 4);
            const bool isx  = (d == 1);
            const bool isy  = (d == 2);
            const float A   = (d == 3) ? aw : ah;
            const float C   = (isx | isy) ? 8.0f : 1.0f;
            const float Bc  = isx ? fi8 : 0.0f;
            const float gk8 = (float)(32 * k);
            const float vv[4] = {v[it].x, v[it].y, v[it].z, v[it].w};
            float r[4];
            #pragma unroll
            for (int e = 0; e < 4; ++e) {
                const float val = vv[e];
                const float ev  = __expf(iswh ? val : -val);   // one exp/elem
                const float s   = __builtin_amdgcn_rcpf(1.0f + ev);
                const float B   = isy ? (gk8 + (float)(8 * e)) : Bc;
                const float rs  = s * C + B;                   // fma
                r[e] = iswh ? ev * A : rs;
            }
            float* p = &lds[d * LDSW + 4 * k];
            p[0] = r[0]; p[1] = r[1]; p[2] = r[2]; p[3] = r[3];
        }
    }
    __syncthreads();

    // ---- phase 2a: batch ALL ds_reads (conflict-free: lane stride 77≡13) ----
    float r[ITERS][4];
    #pragma unroll
    for (int it = 0; it < ITERS; ++it) {
        const int t = tid + it * 256;
        if (it < 6 || t < NV4) {
            const int g0   = t / DDIM;                   // magic-mul div by 85
            const int d    = t - g0 * DDIM;
            const int base = d * LDSW + g0;
            r[it][0] = lds[base];
            r[it][1] = lds[base + ROWV4];                // imm offsets 76/152/228 B
            r[it][2] = lds[base + 2 * ROWV4];
            r[it][3] = lds[base + 3 * ROWV4];
        }
    }

    // ---- phase 2b: coalesced PLAIN stores (the single changed knob) ----
    #pragma unroll
    for (int it = 0; it < ITERS; ++it) {
        const int t = tid + it * 256;
        if (it < 6 || t < NV4) {
            #pragma unroll
            for (int e = 0; e < 4; ++e)
                dst[t + e * NV4] = r[it][e];
        }
    }
}

extern "C" void kernel_launch(void* const* d_in, const int* in_sizes, int n_in,
                              void* d_out, int out_size, void* d_ws, size_t ws_size,
                              hipStream_t stream) {
    const float* x = (const float*)d_in[0];
    float* out = (float*)d_out;
    const int B = in_sizes[0] / (ADIM * DDIM * GG);   // 32
    const int nblocks = B * ADIM * GDIM;              // 7296 = 8 * 912
    yolo_kernel<<<dim3(nblocks), dim3(256), 0, stream>>>(x, out);
}

// Round 10
// 64.851 us; speedup vs baseline: 1.2362x; 1.2362x over previous
//
#include <hip/hip_runtime.h>

#define GDIM 76
#define GG   5776
#define DDIM 85
#define ADIM 3
#define LDSW 77            // lane stride 77 ≡ 13 (mod 32) -> conflict-free scalar LDS access
#define NV4  1615          // = 19 * 85 = DDIM*GDIM/4
#define ROWV4 19
#define PLANE (DDIM * GG)
#define ITERS 7            // 6 full + 1 tail (tid < 79)

// FINAL: round-5 structure (best measured: 64.7 us ≈ 93% of the 377 MB
// copy-equivalent roofline at 6.29 TB/s).
//   - one block per (b,a,i) row-tile, transposed via LDS (both phases
//     conflict-free: lane stride 77 ≡ 13 mod 32; NV4 = 19*85 keeps store-phase
//     d invariant per quad)
//   - all 7 float4 global loads issued back-to-back (latency hiding)
//   - XCD-bijective block swizzle (L2/L3 locality across neighbor tiles)
//   - nontemporal output stores (protects input L3 residency: R9 A/B = +19%)
// Falsified binders: occupancy (R8), LDS op count (R7), bank conflicts (R7),
// DMA gather (R6), tile split (R4), plain stores (R9).
__global__ __launch_bounds__(256, 6) void yolo_kernel(const float* __restrict__ x,
                                                      float* __restrict__ out) {
    // XCD swizzle: 7296 = 8 * 912, bijective; each XCD owns 912 consecutive tiles.
    const int cpx = gridDim.x >> 3;
    const int blk = (blockIdx.x & 7) * cpx + (blockIdx.x >> 3);

    const int i    = blk % GDIM;
    const int slab = blk / GDIM;   // b*A + a
    const int a    = slab % ADIM;
    const int tid  = threadIdx.x;

    __shared__ float lds[DDIM * LDSW];   // 26180 B -> 6 blocks/CU

    const float aw  = (a == 0) ? 10.0f : (a == 1) ? 16.0f : 33.0f;
    const float ah  = (a == 0) ? 13.0f : (a == 1) ? 30.0f : 23.0f;
    const float fi8 = (float)i * 8.0f;

    const float* __restrict__ src = x + (size_t)slab * PLANE + i * GDIM;
    float* __restrict__ dst = out + (size_t)slab * PLANE + (size_t)i * (GDIM * DDIM);

    // ---- phase 1a: issue ALL coalesced float4 loads back-to-back (max MLP) ----
    float4 v[ITERS];
    #pragma unroll
    for (int it = 0; it < ITERS; ++it) {
        const int idx = tid + it * 256;
        if (it < 6 || idx < NV4) {
            const int d = idx / ROWV4;           // magic-mul div by 19
            const int k = idx - d * ROWV4;
            v[it] = *(const float4*)(src + (size_t)d * GG + 4 * k);
        }
    }

    // ---- phase 1b: activation + contiguous LDS writes (~2-way, near-free) ----
    #pragma unroll
    for (int it = 0; it < ITERS; ++it) {
        const int idx = tid + it * 256;
        if (it < 6 || idx < NV4) {
            const int d = idx / ROWV4;
            const int k = idx - d * ROWV4;
            const bool iswh = (d == 3) | (d == 4);
            const bool isx  = (d == 1);
            const bool isy  = (d == 2);
            const float A   = (d == 3) ? aw : ah;
            const float C   = (isx | isy) ? 8.0f : 1.0f;
            const float Bc  = isx ? fi8 : 0.0f;
            const float gk8 = (float)(32 * k);
            const float vv[4] = {v[it].x, v[it].y, v[it].z, v[it].w};
            float r[4];
            #pragma unroll
            for (int e = 0; e < 4; ++e) {
                const float val = vv[e];
                const float ev  = __expf(iswh ? val : -val);   // one exp/elem
                const float s   = __builtin_amdgcn_rcpf(1.0f + ev);
                const float B   = isy ? (gk8 + (float)(8 * e)) : Bc;
                const float rs  = s * C + B;                   // fma
                r[e] = iswh ? ev * A : rs;
            }
            float* p = &lds[d * LDSW + 4 * k];
            p[0] = r[0]; p[1] = r[1]; p[2] = r[2]; p[3] = r[3];
        }
    }
    __syncthreads();

    // ---- phase 2a: batch ALL ds_reads (conflict-free: lane stride 77≡13) ----
    float r[ITERS][4];
    #pragma unroll
    for (int it = 0; it < ITERS; ++it) {
        const int t = tid + it * 256;
        if (it < 6 || t < NV4) {
            const int g0   = t / DDIM;                   // magic-mul div by 85
            const int d    = t - g0 * DDIM;
            const int base = d * LDSW + g0;
            r[it][0] = lds[base];
            r[it][1] = lds[base + ROWV4];                // imm offsets 76/152/228 B
            r[it][2] = lds[base + 2 * ROWV4];
            r[it][3] = lds[base + 3 * ROWV4];
        }
    }

    // ---- phase 2b: coalesced nontemporal stores ----
    #pragma unroll
    for (int it = 0; it < ITERS; ++it) {
        const int t = tid + it * 256;
        if (it < 6 || t < NV4) {
            #pragma unroll
            for (int e = 0; e < 4; ++e)
                __builtin_nontemporal_store(r[it][e], dst + t + e * NV4);
        }
    }
}

extern "C" void kernel_launch(void* const* d_in, const int* in_sizes, int n_in,
                              void* d_out, int out_size, void* d_ws, size_t ws_size,
                              hipStream_t stream) {
    const float* x = (const float*)d_in[0];
    float* out = (float*)d_out;
    const int B = in_sizes[0] / (ADIM * DDIM * GG);   // 32
    const int nblocks = B * ADIM * GDIM;              // 7296 = 8 * 912
    yolo_kernel<<<dim3(nblocks), dim3(256), 0, stream>>>(x, out);
}